// Round 1
// baseline (234.074 us; speedup 1.0000x reference)
//
#include <hip/hip_runtime.h>
#include <hip/hip_bf16.h>

#define NN 128
#define CC 1001
#define RR 51
#define KK 10
#define NK (NN*KK)          // 1280
#define BT_ELEMS (NN*KK*NN*KK)  // 1,638,400
#define W_BIN_C 1.0f
#define MIX_C 10000.0f

// ---------------- top-k per row + unary + Q init ----------------
__global__ __launch_bounds__(256) void topk_kernel(const float* __restrict__ roi,
                                                   int* __restrict__ labels,
                                                   float* __restrict__ unary,
                                                   float* __restrict__ Q0) {
    int a = blockIdx.x;
    int t = threadIdx.x;
    __shared__ float sc[CC];
    __shared__ float rv[256];
    __shared__ int   ri[256];
    for (int c = t; c < CC; c += 256) sc[c] = roi[a * CC + c];
    __syncthreads();
    for (int k = 0; k < KK; ++k) {
        float bv = -1e30f; int bi = CC;  // lower index wins ties (lax.top_k semantics)
        for (int c = t; c < CC; c += 256) {
            float v = sc[c];
            if (v > bv || (v == bv && c < bi)) { bv = v; bi = c; }
        }
        rv[t] = bv; ri[t] = bi;
        __syncthreads();
        for (int s = 128; s > 0; s >>= 1) {
            if (t < s) {
                float v2 = rv[t + s]; int i2 = ri[t + s];
                if (v2 > rv[t] || (v2 == rv[t] && i2 < ri[t])) { rv[t] = v2; ri[t] = i2; }
            }
            __syncthreads();
        }
        if (t == 0) {
            int bi0 = ri[0]; float bv0 = rv[0];
            labels[a * KK + k] = bi0;
            unary[a * KK + k]  = logf(bv0);
            Q0[a * KK + k]     = 1.0f / (float)KK;
            sc[bi0] = -1e30f;
        }
        __syncthreads();
    }
}

// ---------------- raw[a,k,b,l] = sum_r relmat[La_k, Lb_l, r] * exp(rel[a,b,r]) ----------------
// One block per ordered pair (a,b). One wave per (k,l) dot: lanes 0..50 read the
// 51 contiguous floats of the relmat row (coalesced 204B) and shuffle-reduce.
__global__ __launch_bounds__(256) void raw_kernel(const float* __restrict__ rel_scores,
                                                  const float* __restrict__ relmat,
                                                  const int* __restrict__ labels,
                                                  float* __restrict__ bt) {
    int p = blockIdx.x;
    int a = p >> 7;
    int b = p & 127;
    int t = threadIdx.x;
    int wave = t >> 6;
    int lane = t & 63;

    __shared__ int La[KK], Lb[KK];
    if (t < KK)            La[t]       = labels[a * KK + t];
    else if (t < 2 * KK)   Lb[t - KK]  = labels[b * KK + (t - KK)];
    __syncthreads();

    float relv = 0.0f;
    if (lane < RR) relv = expf(rel_scores[(a * NN + b) * RR + lane]);

    for (int kl = wave; kl < KK * KK; kl += 4) {
        int k = kl / KK, l = kl % KK;
        float v = 0.0f;
        if (lane < RR) {
            int idx = (La[k] * CC + Lb[l]) * RR + lane;
            v = relmat[idx] * relv;
        }
        #pragma unroll
        for (int off = 32; off > 0; off >>= 1) v += __shfl_down(v, off, 64);
        if (lane == 0) bt[((a * KK + k) * NN + b) * KK + l] = v;
    }
}

// ---------------- bt = log(0.5*(raw + raw^T)); zero when a==b ----------------
__global__ __launch_bounds__(256) void symlog_kernel(float* __restrict__ bt) {
    int i = blockIdx.x * 256 + threadIdx.x;
    if (i >= BT_ELEMS) return;
    int l = i % KK;
    int b = (i / KK) % NN;
    int k = (i / (KK * NN)) % KK;
    int a = i / (KK * NN * KK);
    if (a > b) return;
    if (a == b) { bt[i] = 0.0f; return; }
    int j = ((b * KK + l) * NN + a) * KK + k;
    float x = bt[i], y = bt[j];
    float v = logf(0.5f * (x + y));
    bt[i] = v;
    bt[j] = v;
}

// ---------------- one mean-field round: msg = bt @ Q ; Q = softmax(msg + unary) ----------------
__global__ __launch_bounds__(256) void round_kernel(const float* __restrict__ bt,
                                                    const float* __restrict__ unary,
                                                    const float* __restrict__ Qin,
                                                    float* __restrict__ Qout) {
    int a = blockIdx.x;
    int t = threadIdx.x;
    __shared__ float sQ[NK];
    __shared__ float smsg[KK];
    __shared__ float sred[256];
    for (int i = t; i < NK; i += 256) sQ[i] = Qin[i];
    __syncthreads();
    for (int k = 0; k < KK; ++k) {
        const float* row = bt + (a * KK + k) * NK;
        float acc = 0.0f;
        for (int i = t; i < NK; i += 256) acc += row[i] * sQ[i];
        sred[t] = acc;
        __syncthreads();
        for (int s = 128; s > 0; s >>= 1) {
            if (t < s) sred[t] += sred[t + s];
            __syncthreads();
        }
        if (t == 0) smsg[k] = sred[0];
        __syncthreads();
    }
    if (t == 0) {
        float e[KK];
        float m = -1e30f;
        for (int k = 0; k < KK; ++k) {
            float v = W_BIN_C * smsg[k] + unary[a * KK + k];
            e[k] = v;
            if (v > m) m = v;
        }
        float s = 0.0f;
        for (int k = 0; k < KK; ++k) { e[k] = expf(e[k] - m); s += e[k]; }
        for (int k = 0; k < KK; ++k) Qout[a * KK + k] = e[k] / s;
    }
}

// ---------------- out = (roi + MIX*scatter(Q)) / (1+MIX) ----------------
__global__ __launch_bounds__(256) void out_kernel(const float* __restrict__ roi,
                                                  const int* __restrict__ labels,
                                                  const float* __restrict__ Qf,
                                                  float* __restrict__ out) {
    int a = blockIdx.x;
    int t = threadIdx.x;
    __shared__ int   sL[KK];
    __shared__ float sQ[KK];
    if (t < KK) { sL[t] = labels[a * KK + t]; sQ[t] = Qf[a * KK + t]; }
    __syncthreads();
    for (int c = t; c < CC; c += 256) {
        float q = 0.0f;
        #pragma unroll
        for (int k = 0; k < KK; ++k) if (sL[k] == c) q = sQ[k];
        out[a * CC + c] = (roi[a * CC + c] + MIX_C * q) / (1.0f + MIX_C);
    }
}

extern "C" void kernel_launch(void* const* d_in, const int* in_sizes, int n_in,
                              void* d_out, int out_size, void* d_ws, size_t ws_size,
                              hipStream_t stream) {
    const float* roi    = (const float*)d_in[0];  // (128, 1001)
    const float* rel    = (const float*)d_in[1];  // (16384, 51)
    const float* relmat = (const float*)d_in[2];  // (1001, 1001, 51)
    float* out = (float*)d_out;

    // workspace layout
    char* ws = (char*)d_ws;
    float* bt     = (float*)ws;                                  // 6,553,600 B
    int*   labels = (int*)(ws + (size_t)BT_ELEMS * 4);           // 5,120 B
    float* unary  = (float*)(ws + (size_t)BT_ELEMS * 4 + 5120);
    float* Q0     = unary + NK;
    float* Q1     = Q0 + NK;

    topk_kernel<<<NN, 256, 0, stream>>>(roi, labels, unary, Q0);
    raw_kernel<<<NN * NN, 256, 0, stream>>>(rel, relmat, labels, bt);
    symlog_kernel<<<(BT_ELEMS + 255) / 256, 256, 0, stream>>>(bt);
    round_kernel<<<NN, 256, 0, stream>>>(bt, unary, Q0, Q1);
    round_kernel<<<NN, 256, 0, stream>>>(bt, unary, Q1, Q0);
    round_kernel<<<NN, 256, 0, stream>>>(bt, unary, Q0, Q1);
    out_kernel<<<NN, 256, 0, stream>>>(roi, labels, Q1, out);
}

// Round 2
// 155.487 us; speedup vs baseline: 1.5054x; 1.5054x over previous
//
#include <hip/hip_runtime.h>
#include <hip/hip_bf16.h>

#define NN 128
#define CC 1001
#define RR 51
#define KK 10
#define NK (NN*KK)              // 1280
#define BT_ELEMS (NN*KK*NN*KK) // 1,638,400
#define W_BIN_C 1.0f
#define MIX_C 10000.0f

typedef float f4_t __attribute__((ext_vector_type(4)));
typedef f4_t f4u __attribute__((aligned(4)));   // 4-byte-aligned float4 load

// ---------------- top-k per row + unary + Q init ----------------
__global__ __launch_bounds__(256) void topk_kernel(const float* __restrict__ roi,
                                                   int* __restrict__ labels,
                                                   float* __restrict__ unary,
                                                   float* __restrict__ Q0) {
    int a = blockIdx.x;
    int t = threadIdx.x;
    __shared__ float sc[CC];
    __shared__ float rv[256];
    __shared__ int   ri[256];
    for (int c = t; c < CC; c += 256) sc[c] = roi[a * CC + c];
    __syncthreads();
    for (int k = 0; k < KK; ++k) {
        float bv = -1e30f; int bi = CC;  // lower index wins ties (lax.top_k semantics)
        for (int c = t; c < CC; c += 256) {
            float v = sc[c];
            if (v > bv || (v == bv && c < bi)) { bv = v; bi = c; }
        }
        rv[t] = bv; ri[t] = bi;
        __syncthreads();
        for (int s = 128; s > 0; s >>= 1) {
            if (t < s) {
                float v2 = rv[t + s]; int i2 = ri[t + s];
                if (v2 > rv[t] || (v2 == rv[t] && i2 < ri[t])) { rv[t] = v2; ri[t] = i2; }
            }
            __syncthreads();
        }
        if (t == 0) {
            int bi0 = ri[0]; float bv0 = rv[0];
            labels[a * KK + k] = bi0;
            unary[a * KK + k]  = logf(bv0);
            Q0[a * KK + k]     = 1.0f / (float)KK;
            sc[bi0] = -1e30f;
        }
        __syncthreads();
    }
}

// ---------------- raw[a,k,b,l] = sum_r relmat[La_k, Lb_l, r] * exp(rel[a,b,r]) ----------------
// One block per ordered pair (a,b). Each 16-lane group owns one (k,l) row:
// lanes 0..11 load float4 at r=4*sub, lane 12 loads r=47..50 with coeff.x=0
// (r=47 already counted by lane 11). One dwordx4 VMEM fetches 4 rows/wave;
// unroll x2 keeps ~1.6KB in flight per wave.
__global__ __launch_bounds__(256) void raw_kernel(const float* __restrict__ rel_scores,
                                                  const float* __restrict__ relmat,
                                                  const int* __restrict__ labels,
                                                  float* __restrict__ bt) {
    int p = blockIdx.x;
    int a = p >> 7;
    int b = p & 127;
    int t = threadIdx.x;
    int wave = t >> 6;
    int lane = t & 63;
    int grp  = lane >> 4;   // 0..3 : row within 4-row group
    int sub  = lane & 15;   // 0..15 : position within row

    __shared__ int   La[KK], Lb[KK];
    __shared__ int   base[KK * KK];    // relmat row start (element index)
    __shared__ int   obase[KK * KK];   // bt output element index
    __shared__ float sexp[RR];

    if (t < KK)          La[t]      = labels[a * KK + t];
    else if (t < 2 * KK) Lb[t - KK] = labels[b * KK + (t - KK)];
    if (t >= 128 && t < 128 + RR)
        sexp[t - 128] = expf(rel_scores[(a * NN + b) * RR + (t - 128)]);
    __syncthreads();
    if (t < KK * KK) {
        int k = t / KK, l = t % KK;
        base[t]  = (La[k] * CC + Lb[l]) * RR;
        obase[t] = ((a * KK + k) * NN + b) * KK + l;
    }
    __syncthreads();

    // per-lane coefficient vector and element offset
    int roff;
    f4_t rv;
    bool active = (sub < 13);
    if (sub < 12) {
        roff = sub * 4;
        rv.x = sexp[roff]; rv.y = sexp[roff + 1]; rv.z = sexp[roff + 2]; rv.w = sexp[roff + 3];
    } else if (sub == 12) {
        roff = 47;
        rv.x = 0.0f; rv.y = sexp[48]; rv.z = sexp[49]; rv.w = sexp[50];
    } else {
        roff = 0;
        rv.x = rv.y = rv.z = rv.w = 0.0f;
    }

    for (int g = wave; g < 25; g += 8) {
        int kl0 = g * 4 + grp;
        int g1  = g + 4;
        bool h1 = (g1 < 25);
        int kl1 = h1 ? g1 * 4 + grp : kl0;

        f4_t m0 = {0.f, 0.f, 0.f, 0.f};
        f4_t m1 = {0.f, 0.f, 0.f, 0.f};
        if (active)        m0 = *(const f4u*)(relmat + base[kl0] + roff);
        if (active && h1)  m1 = *(const f4u*)(relmat + base[kl1] + roff);

        float v0 = m0.x * rv.x + m0.y * rv.y + m0.z * rv.z + m0.w * rv.w;
        float v1 = m1.x * rv.x + m1.y * rv.y + m1.z * rv.z + m1.w * rv.w;
        #pragma unroll
        for (int mask = 8; mask > 0; mask >>= 1) {
            v0 += __shfl_xor(v0, mask, 64);
            v1 += __shfl_xor(v1, mask, 64);
        }
        if (sub == 0) {
            bt[obase[kl0]] = v0;
            if (h1) bt[obase[kl1]] = v1;
        }
    }
}

// ---------------- bt = log(0.5*(raw + raw^T)); zero when a==b ----------------
__global__ __launch_bounds__(256) void symlog_kernel(float* __restrict__ bt) {
    int i = blockIdx.x * 256 + threadIdx.x;
    if (i >= BT_ELEMS) return;
    int l = i % KK;
    int b = (i / KK) % NN;
    int k = (i / (KK * NN)) % KK;
    int a = i / (KK * NN * KK);
    if (a > b) return;
    if (a == b) { bt[i] = 0.0f; return; }
    int j = ((b * KK + l) * NN + a) * KK + k;
    float x = bt[i], y = bt[j];
    float v = logf(0.5f * (x + y));
    bt[i] = v;
    bt[j] = v;
}

// ---------------- one mean-field round: msg = bt @ Q ; Q = softmax(msg + unary) ----------------
__global__ __launch_bounds__(256) void round_kernel(const float* __restrict__ bt,
                                                    const float* __restrict__ unary,
                                                    const float* __restrict__ Qin,
                                                    float* __restrict__ Qout) {
    int a = blockIdx.x;
    int t = threadIdx.x;
    __shared__ float sQ[NK];
    __shared__ float smsg[KK];
    __shared__ float sred[256];
    for (int i = t; i < NK; i += 256) sQ[i] = Qin[i];
    __syncthreads();
    for (int k = 0; k < KK; ++k) {
        const float* row = bt + (a * KK + k) * NK;
        float acc = 0.0f;
        for (int i = t; i < NK; i += 256) acc += row[i] * sQ[i];
        sred[t] = acc;
        __syncthreads();
        for (int s = 128; s > 0; s >>= 1) {
            if (t < s) sred[t] += sred[t + s];
            __syncthreads();
        }
        if (t == 0) smsg[k] = sred[0];
        __syncthreads();
    }
    if (t == 0) {
        float e[KK];
        float m = -1e30f;
        for (int k = 0; k < KK; ++k) {
            float v = W_BIN_C * smsg[k] + unary[a * KK + k];
            e[k] = v;
            if (v > m) m = v;
        }
        float s = 0.0f;
        for (int k = 0; k < KK; ++k) { e[k] = expf(e[k] - m); s += e[k]; }
        for (int k = 0; k < KK; ++k) Qout[a * KK + k] = e[k] / s;
    }
}

// ---------------- out = (roi + MIX*scatter(Q)) / (1+MIX) ----------------
__global__ __launch_bounds__(256) void out_kernel(const float* __restrict__ roi,
                                                  const int* __restrict__ labels,
                                                  const float* __restrict__ Qf,
                                                  float* __restrict__ out) {
    int a = blockIdx.x;
    int t = threadIdx.x;
    __shared__ int   sL[KK];
    __shared__ float sQ[KK];
    if (t < KK) { sL[t] = labels[a * KK + t]; sQ[t] = Qf[a * KK + t]; }
    __syncthreads();
    for (int c = t; c < CC; c += 256) {
        float q = 0.0f;
        #pragma unroll
        for (int k = 0; k < KK; ++k) if (sL[k] == c) q = sQ[k];
        out[a * CC + c] = (roi[a * CC + c] + MIX_C * q) / (1.0f + MIX_C);
    }
}

extern "C" void kernel_launch(void* const* d_in, const int* in_sizes, int n_in,
                              void* d_out, int out_size, void* d_ws, size_t ws_size,
                              hipStream_t stream) {
    const float* roi    = (const float*)d_in[0];  // (128, 1001)
    const float* rel    = (const float*)d_in[1];  // (16384, 51)
    const float* relmat = (const float*)d_in[2];  // (1001, 1001, 51)
    float* out = (float*)d_out;

    // workspace layout
    char* ws = (char*)d_ws;
    float* bt     = (float*)ws;                                  // 6,553,600 B
    int*   labels = (int*)(ws + (size_t)BT_ELEMS * 4);           // 5,120 B
    float* unary  = (float*)(ws + (size_t)BT_ELEMS * 4 + 5120);
    float* Q0     = unary + NK;
    float* Q1     = Q0 + NK;

    topk_kernel<<<NN, 256, 0, stream>>>(roi, labels, unary, Q0);
    raw_kernel<<<NN * NN, 256, 0, stream>>>(rel, relmat, labels, bt);
    symlog_kernel<<<(BT_ELEMS + 255) / 256, 256, 0, stream>>>(bt);
    round_kernel<<<NN, 256, 0, stream>>>(bt, unary, Q0, Q1);
    round_kernel<<<NN, 256, 0, stream>>>(bt, unary, Q1, Q0);
    round_kernel<<<NN, 256, 0, stream>>>(bt, unary, Q0, Q1);
    out_kernel<<<NN, 256, 0, stream>>>(roi, labels, Q1, out);
}

// Round 3
// 102.111 us; speedup vs baseline: 2.2923x; 1.5227x over previous
//
#include <hip/hip_runtime.h>
#include <hip/hip_bf16.h>

#define NN 128
#define CC 1001
#define RR 51
#define KK 10
#define NK (NN*KK)              // 1280
#define BT_ELEMS (NN*KK*NN*KK) // 1,638,400
#define W_BIN_C 1.0f
#define MIX_C 10000.0f

typedef float f4_t __attribute__((ext_vector_type(4)));
typedef f4_t f4u __attribute__((aligned(4)));   // 4-byte-aligned float4 load

// ---------------- top-k per row + unary + Q init ----------------
__global__ __launch_bounds__(256) void topk_kernel(const float* __restrict__ roi,
                                                   int* __restrict__ labels,
                                                   float* __restrict__ unary,
                                                   float* __restrict__ Q0) {
    int a = blockIdx.x, t = threadIdx.x;
    int wave = t >> 6, lane = t & 63;
    __shared__ float sc[CC];
    __shared__ float wv[4];
    __shared__ int   wi[4];
    for (int c = t; c < CC; c += 256) sc[c] = roi[a * CC + c];
    __syncthreads();
    for (int k = 0; k < KK; ++k) {
        float bv = -1e30f; int bi = CC;
        for (int c = t; c < CC; c += 256) {
            float v = sc[c];
            if (v > bv) { bv = v; bi = c; }   // ascending scan: strict > keeps lowest index on tie
        }
        #pragma unroll
        for (int m = 32; m > 0; m >>= 1) {
            float v2 = __shfl_xor(bv, m, 64);
            int   i2 = __shfl_xor(bi, m, 64);
            if (v2 > bv || (v2 == bv && i2 < bi)) { bv = v2; bi = i2; }
        }
        if (lane == 0) { wv[wave] = bv; wi[wave] = bi; }
        __syncthreads();
        if (t == 0) {
            float fbv = wv[0]; int fbi = wi[0];
            #pragma unroll
            for (int w = 1; w < 4; ++w)
                if (wv[w] > fbv || (wv[w] == fbv && wi[w] < fbi)) { fbv = wv[w]; fbi = wi[w]; }
            labels[a * KK + k] = fbi;
            unary[a * KK + k]  = logf(fbv);
            Q0[a * KK + k]     = 1.0f / (float)KK;
            sc[fbi] = -1e30f;
        }
        __syncthreads();
    }
}

// ---------------- fused raw + symmetrize + log ----------------
// One block per unordered pair {a,b}, a<=b (2D grid, a>b exits).
// bt[a,k,b,l] = bt[b,l,a,k] = log(0.5*(dot(relmat[La_k,Lb_l,:], eAB) +
//                                       dot(relmat[Lb_l,La_k,:], eBA)))
// Each 16-lane group owns one (k,l): lanes 0..12 cover the 51-float rows with
// dwordx4 (lane 12 at r=47 with coeff.x=0); BOTH directional dots are summed
// into ONE value before the 4-step shuffle reduce. Unroll x4 => 8 loads in flight.
__global__ __launch_bounds__(256) void pair_kernel(const float* __restrict__ rel_scores,
                                                   const float* __restrict__ relmat,
                                                   const int* __restrict__ labels,
                                                   float* __restrict__ bt) {
    int a = blockIdx.y, b = blockIdx.x;
    if (a > b) return;
    int t = threadIdx.x;
    if (a == b) {
        if (t < KK * KK) {
            int k = t / KK, l = t % KK;
            bt[((a * KK + k) * NN + a) * KK + l] = 0.0f;
        }
        return;
    }

    __shared__ int   La[KK], Lb[KK];
    __shared__ int   baseAB[KK * KK], baseBA[KK * KK];
    __shared__ int   oAB[KK * KK],   oBA[KK * KK];
    __shared__ float eAB[RR], eBA[RR];

    if (t < KK)            La[t]      = labels[a * KK + t];
    else if (t < 2 * KK)   Lb[t - KK] = labels[b * KK + (t - KK)];
    if (t >= 64  && t < 64 + RR)  eAB[t - 64]  = expf(rel_scores[(a * NN + b) * RR + (t - 64)]);
    if (t >= 128 && t < 128 + RR) eBA[t - 128] = expf(rel_scores[(b * NN + a) * RR + (t - 128)]);
    __syncthreads();
    if (t < KK * KK) {
        int k = t / KK, l = t % KK;
        baseAB[t] = (La[k] * CC + Lb[l]) * RR;
        baseBA[t] = (Lb[l] * CC + La[k]) * RR;
        oAB[t]    = ((a * KK + k) * NN + b) * KK + l;
        oBA[t]    = ((b * KK + l) * NN + a) * KK + k;
    }
    __syncthreads();

    int gid = t >> 4;      // 0..15, 16-lane group (aligned within wave)
    int sub = t & 15;

    int roff; f4_t cAB, cBA;
    bool active = (sub < 13);
    if (sub < 12) {
        roff = sub * 4;
        cAB.x = eAB[roff]; cAB.y = eAB[roff+1]; cAB.z = eAB[roff+2]; cAB.w = eAB[roff+3];
        cBA.x = eBA[roff]; cBA.y = eBA[roff+1]; cBA.z = eBA[roff+2]; cBA.w = eBA[roff+3];
    } else if (sub == 12) {
        roff = 47;   // r=47 already counted by lane 11 -> x coeff zeroed
        cAB.x = 0.f; cAB.y = eAB[48]; cAB.z = eAB[49]; cAB.w = eAB[50];
        cBA.x = 0.f; cBA.y = eBA[48]; cBA.z = eBA[49]; cBA.w = eBA[50];
    } else {
        roff = 0;
        cAB.x = cAB.y = cAB.z = cAB.w = 0.f;
        cBA.x = cBA.y = cBA.z = cBA.w = 0.f;
    }

    #pragma unroll
    for (int p = 0; p < 2; ++p) {
        int kl0 = gid + p * 64;
        f4_t mA[4], mB[4];
        #pragma unroll
        for (int u = 0; u < 4; ++u) {
            int kl = kl0 + u * 16;
            bool h = (kl < 100) && active;
            int kls = (kl < 100) ? kl : 0;
            f4_t zero; zero.x = zero.y = zero.z = zero.w = 0.f;
            mA[u] = h ? *(const f4u*)(relmat + baseAB[kls] + roff) : zero;
            mB[u] = h ? *(const f4u*)(relmat + baseBA[kls] + roff) : zero;
        }
        float s[4];
        #pragma unroll
        for (int u = 0; u < 4; ++u) {
            s[u] = mA[u].x * cAB.x + mA[u].y * cAB.y + mA[u].z * cAB.z + mA[u].w * cAB.w
                 + mB[u].x * cBA.x + mB[u].y * cBA.y + mB[u].z * cBA.z + mB[u].w * cBA.w;
        }
        #pragma unroll
        for (int m = 8; m > 0; m >>= 1) {
            #pragma unroll
            for (int u = 0; u < 4; ++u) s[u] += __shfl_xor(s[u], m, 64);
        }
        if (sub == 0) {
            #pragma unroll
            for (int u = 0; u < 4; ++u) {
                int kl = kl0 + u * 16;
                if (kl < 100) {
                    float v = logf(0.5f * s[u]);
                    bt[oAB[kl]] = v;
                    bt[oBA[kl]] = v;
                }
            }
        }
    }
}

// ---------------- one mean-field round: msg = bt @ Q ; Q = softmax(msg + unary) ----------------
__global__ __launch_bounds__(256) void round_kernel(const float* __restrict__ bt,
                                                    const float* __restrict__ unary,
                                                    const float* __restrict__ Qin,
                                                    float* __restrict__ Qout) {
    int a = blockIdx.x, t = threadIdx.x;
    int wave = t >> 6, lane = t & 63;
    __shared__ float sQ[NK];
    __shared__ float smsg[KK];
    for (int i = t; i < NK / 4; i += 256) ((f4_t*)sQ)[i] = ((const f4_t*)Qin)[i];
    __syncthreads();
    const f4_t* q4 = (const f4_t*)sQ;
    for (int k = wave; k < KK; k += 4) {
        const f4_t* row = (const f4_t*)(bt + (a * KK + k) * NK);
        float acc = 0.f;
        #pragma unroll
        for (int j = 0; j < 5; ++j) {
            f4_t r = row[lane + 64 * j];
            f4_t q = q4[lane + 64 * j];
            acc += r.x * q.x + r.y * q.y + r.z * q.z + r.w * q.w;
        }
        #pragma unroll
        for (int m = 32; m > 0; m >>= 1) acc += __shfl_xor(acc, m, 64);
        if (lane == 0) smsg[k] = acc;
    }
    __syncthreads();
    if (t == 0) {
        float e[KK], m = -1e30f;
        #pragma unroll
        for (int k = 0; k < KK; ++k) {
            float v = W_BIN_C * smsg[k] + unary[a * KK + k];
            e[k] = v;
            if (v > m) m = v;
        }
        float s = 0.f;
        #pragma unroll
        for (int k = 0; k < KK; ++k) { e[k] = expf(e[k] - m); s += e[k]; }
        #pragma unroll
        for (int k = 0; k < KK; ++k) Qout[a * KK + k] = e[k] / s;
    }
}

// ---------------- out = (roi + MIX*scatter(Q)) / (1+MIX) ----------------
__global__ __launch_bounds__(256) void out_kernel(const float* __restrict__ roi,
                                                  const int* __restrict__ labels,
                                                  const float* __restrict__ Qf,
                                                  float* __restrict__ out) {
    int a = blockIdx.x;
    int t = threadIdx.x;
    __shared__ int   sL[KK];
    __shared__ float sQ[KK];
    if (t < KK) { sL[t] = labels[a * KK + t]; sQ[t] = Qf[a * KK + t]; }
    __syncthreads();
    for (int c = t; c < CC; c += 256) {
        float q = 0.0f;
        #pragma unroll
        for (int k = 0; k < KK; ++k) if (sL[k] == c) q = sQ[k];
        out[a * CC + c] = (roi[a * CC + c] + MIX_C * q) / (1.0f + MIX_C);
    }
}

extern "C" void kernel_launch(void* const* d_in, const int* in_sizes, int n_in,
                              void* d_out, int out_size, void* d_ws, size_t ws_size,
                              hipStream_t stream) {
    const float* roi    = (const float*)d_in[0];  // (128, 1001)
    const float* rel    = (const float*)d_in[1];  // (16384, 51)
    const float* relmat = (const float*)d_in[2];  // (1001, 1001, 51)
    float* out = (float*)d_out;

    // workspace layout (all 16B-aligned)
    char* ws = (char*)d_ws;
    float* bt     = (float*)ws;                                   // 6,553,600 B
    int*   labels = (int*)(ws + (size_t)BT_ELEMS * 4);            // 5,120 B
    float* unary  = (float*)(ws + (size_t)BT_ELEMS * 4 + 5120);   // 5,120 B
    float* Q0     = unary + NK;
    float* Q1     = Q0 + NK;

    topk_kernel<<<NN, 256, 0, stream>>>(roi, labels, unary, Q0);
    pair_kernel<<<dim3(NN, NN), 256, 0, stream>>>(rel, relmat, labels, bt);
    round_kernel<<<NN, 256, 0, stream>>>(bt, unary, Q0, Q1);
    round_kernel<<<NN, 256, 0, stream>>>(bt, unary, Q1, Q0);
    round_kernel<<<NN, 256, 0, stream>>>(bt, unary, Q0, Q1);
    out_kernel<<<NN, 256, 0, stream>>>(roi, labels, Q1, out);
}

// Round 4
// 94.953 us; speedup vs baseline: 2.4651x; 1.0754x over previous
//
#include <hip/hip_runtime.h>
#include <hip/hip_bf16.h>

#define NN 128
#define CC 1001
#define RR 51
#define KK 10
#define NK (NN*KK)              // 1280
#define BT_ELEMS (NN*KK*NN*KK) // 1,638,400
#define W_BIN_C 1.0f
#define MIX_C 10000.0f

typedef float f4_t __attribute__((ext_vector_type(4)));
typedef f4_t f4u __attribute__((aligned(4)));   // 4-byte-aligned float4 load

// ---------------- top-k: one wave per row, all-register ----------------
__global__ __launch_bounds__(64) void topk_kernel(const float* __restrict__ roi,
                                                  int* __restrict__ labels,
                                                  float* __restrict__ unary) {
    int a = blockIdx.x, lane = threadIdx.x;
    const float* rowp = roi + a * CC;
    float v[16];
    #pragma unroll
    for (int j = 0; j < 16; ++j) {
        int c = lane + 64 * j;
        v[j] = (c < CC) ? rowp[c] : -1e30f;
    }
    for (int k = 0; k < KK; ++k) {
        float bv = v[0]; int bj = 0;
        #pragma unroll
        for (int j = 1; j < 16; ++j) if (v[j] > bv) { bv = v[j]; bj = j; }  // ascending: lowest j on tie
        int bc = lane + 64 * bj;
        #pragma unroll
        for (int m = 32; m > 0; m >>= 1) {
            float v2 = __shfl_xor(bv, m, 64);
            int   c2 = __shfl_xor(bc, m, 64);
            if (v2 > bv || (v2 == bv && c2 < bc)) { bv = v2; bc = c2; }
        }
        if (lane == (bc & 63)) {
            int j = bc >> 6;
            #pragma unroll
            for (int jj = 0; jj < 16; ++jj) if (jj == j) v[jj] = -1e30f;  // static index clear
        }
        if (lane == 0) {
            labels[a * KK + k] = bc;
            unary[a * KK + k]  = logf(bv);
        }
    }
}

// ---------------- fused raw + symmetrize + log ----------------
// One block per unordered pair {a,b}. 8-lane group per (k,l):
//   lanes 0..5: two f4 at r=8s, 8s+4; lane 6: f4 at r=47 with x-coeff zeroed;
//   both directional dots summed into one scalar; 3-step shuffle reduce.
// 16 dwordx4 in flight per thread (4 kl-slots x 2 dir x 2 loads).
__global__ __launch_bounds__(256) void pair_kernel(const float* __restrict__ rel_scores,
                                                   const float* __restrict__ relmat,
                                                   const int* __restrict__ labels,
                                                   float* __restrict__ bt) {
    int a = blockIdx.y, b = blockIdx.x;
    if (a > b) return;
    int t = threadIdx.x;
    if (a == b) {
        if (t < 100) {
            int k = t / 10, l = t % 10;
            bt[((a * KK + k) * NN + a) * KK + l] = 0.0f;
        }
        return;
    }

    __shared__ int   La[KK], Lb[KK];
    __shared__ int   baseAB[100], baseBA[100], oAB[100], oBA[100];
    __shared__ float eAB[RR], eBA[RR];

    if (t < KK)            La[t]      = labels[a * KK + t];
    else if (t < 2 * KK)   Lb[t - KK] = labels[b * KK + (t - KK)];
    if (t >= 64  && t < 64 + RR)  eAB[t - 64]  = expf(rel_scores[(a * NN + b) * RR + (t - 64)]);
    if (t >= 128 && t < 128 + RR) eBA[t - 128] = expf(rel_scores[(b * NN + a) * RR + (t - 128)]);
    __syncthreads();
    if (t < 100) {
        int k = t / 10, l = t % 10;
        baseAB[t] = (La[k] * CC + Lb[l]) * RR;
        baseBA[t] = (Lb[l] * CC + La[k]) * RR;
        oAB[t]    = ((a * KK + k) * NN + b) * KK + l;
        oBA[t]    = ((b * KK + l) * NN + a) * KK + k;
    }
    __syncthreads();

    int gid = t >> 3;      // 0..31
    int sub = t & 7;
    bool act0 = sub < 7, act1 = sub < 6;
    int r0 = (sub < 6) ? sub * 8 : 47;   // lane 6: r=47..50, x zeroed (47 counted by lane 5)
    int r1 = sub * 8 + 4;

    f4_t zero; zero.x = zero.y = zero.z = zero.w = 0.f;
    f4_t c0A = zero, c1A = zero, c0B = zero, c1B = zero;
    if (sub < 6) {
        c0A.x = eAB[r0];   c0A.y = eAB[r0+1]; c0A.z = eAB[r0+2]; c0A.w = eAB[r0+3];
        c1A.x = eAB[r1];   c1A.y = eAB[r1+1]; c1A.z = eAB[r1+2]; c1A.w = eAB[r1+3];
        c0B.x = eBA[r0];   c0B.y = eBA[r0+1]; c0B.z = eBA[r0+2]; c0B.w = eBA[r0+3];
        c1B.x = eBA[r1];   c1B.y = eBA[r1+1]; c1B.z = eBA[r1+2]; c1B.w = eBA[r1+3];
    } else if (sub == 6) {
        c0A.x = 0.f; c0A.y = eAB[48]; c0A.z = eAB[49]; c0A.w = eAB[50];
        c0B.x = 0.f; c0B.y = eBA[48]; c0B.z = eBA[49]; c0B.w = eBA[50];
    }

    f4_t A0[4], A1[4], B0[4], B1[4];
    #pragma unroll
    for (int u = 0; u < 4; ++u) {
        int kl = gid + 32 * u;
        bool h = (kl < 100);
        int kls = h ? kl : 0;
        int bA = baseAB[kls], bB = baseBA[kls];
        A0[u] = (h && act0) ? *(const f4u*)(relmat + bA + r0) : zero;
        A1[u] = (h && act1) ? *(const f4u*)(relmat + bA + r1) : zero;
        B0[u] = (h && act0) ? *(const f4u*)(relmat + bB + r0) : zero;
        B1[u] = (h && act1) ? *(const f4u*)(relmat + bB + r1) : zero;
    }
    float s[4];
    #pragma unroll
    for (int u = 0; u < 4; ++u) {
        s[u] = A0[u].x*c0A.x + A0[u].y*c0A.y + A0[u].z*c0A.z + A0[u].w*c0A.w
             + A1[u].x*c1A.x + A1[u].y*c1A.y + A1[u].z*c1A.z + A1[u].w*c1A.w
             + B0[u].x*c0B.x + B0[u].y*c0B.y + B0[u].z*c0B.z + B0[u].w*c0B.w
             + B1[u].x*c1B.x + B1[u].y*c1B.y + B1[u].z*c1B.z + B1[u].w*c1B.w;
    }
    #pragma unroll
    for (int m = 4; m > 0; m >>= 1) {
        #pragma unroll
        for (int u = 0; u < 4; ++u) s[u] += __shfl_xor(s[u], m, 64);
    }
    if (sub == 0) {
        #pragma unroll
        for (int u = 0; u < 4; ++u) {
            int kl = gid + 32 * u;
            if (kl < 100) {
                float vv = logf(0.5f * s[u]);
                bt[oAB[kl]] = vv;
                bt[oBA[kl]] = vv;
            }
        }
    }
}

// ---------------- mean-field round: 10 waves, wave k owns row k ----------------
__global__ __launch_bounds__(640) void round_kernel(const float* __restrict__ bt,
                                                    const float* __restrict__ unary,
                                                    const float* __restrict__ Qin,
                                                    float* __restrict__ Qout,
                                                    int uniform) {
    int a = blockIdx.x, t = threadIdx.x;
    int wave = t >> 6, lane = t & 63;
    __shared__ float sQ[NK];
    __shared__ float smsg[KK];
    if (!uniform && t < NK / 4) ((f4_t*)sQ)[t] = ((const f4_t*)Qin)[t];
    __syncthreads();
    const f4_t* row = (const f4_t*)(bt + (a * KK + wave) * NK);
    float acc = 0.f;
    if (uniform) {
        #pragma unroll
        for (int j = 0; j < 5; ++j) {
            f4_t r = row[lane + 64 * j];
            acc += r.x + r.y + r.z + r.w;
        }
        acc *= (1.0f / (float)KK);
    } else {
        const f4_t* q4 = (const f4_t*)sQ;
        #pragma unroll
        for (int j = 0; j < 5; ++j) {
            f4_t r = row[lane + 64 * j];
            f4_t q = q4[lane + 64 * j];
            acc += r.x * q.x + r.y * q.y + r.z * q.z + r.w * q.w;
        }
    }
    #pragma unroll
    for (int m = 32; m > 0; m >>= 1) acc += __shfl_xor(acc, m, 64);
    if (lane == 0) smsg[wave] = acc;
    __syncthreads();
    if (t == 0) {
        float e[KK], m = -1e30f;
        #pragma unroll
        for (int k = 0; k < KK; ++k) {
            float v = W_BIN_C * smsg[k] + unary[a * KK + k];
            e[k] = v;
            if (v > m) m = v;
        }
        float s = 0.f;
        #pragma unroll
        for (int k = 0; k < KK; ++k) { e[k] = expf(e[k] - m); s += e[k]; }
        #pragma unroll
        for (int k = 0; k < KK; ++k) Qout[a * KK + k] = e[k] / s;
    }
}

// ---------------- final round fused with output scatter/mix ----------------
__global__ __launch_bounds__(640) void round_out_kernel(const float* __restrict__ bt,
                                                        const float* __restrict__ unary,
                                                        const float* __restrict__ Qin,
                                                        const float* __restrict__ roi,
                                                        const int* __restrict__ labels,
                                                        float* __restrict__ out) {
    int a = blockIdx.x, t = threadIdx.x;
    int wave = t >> 6, lane = t & 63;
    __shared__ float sQ[NK];
    __shared__ float smsg[KK];
    __shared__ float sq[KK];
    __shared__ int   sL[KK];
    if (t < NK / 4) ((f4_t*)sQ)[t] = ((const f4_t*)Qin)[t];
    if (t >= 320 && t < 320 + KK) sL[t - 320] = labels[a * KK + (t - 320)];
    __syncthreads();
    const f4_t* row = (const f4_t*)(bt + (a * KK + wave) * NK);
    const f4_t* q4  = (const f4_t*)sQ;
    float acc = 0.f;
    #pragma unroll
    for (int j = 0; j < 5; ++j) {
        f4_t r = row[lane + 64 * j];
        f4_t q = q4[lane + 64 * j];
        acc += r.x * q.x + r.y * q.y + r.z * q.z + r.w * q.w;
    }
    #pragma unroll
    for (int m = 32; m > 0; m >>= 1) acc += __shfl_xor(acc, m, 64);
    if (lane == 0) smsg[wave] = acc;
    __syncthreads();
    if (t == 0) {
        float e[KK], m = -1e30f;
        #pragma unroll
        for (int k = 0; k < KK; ++k) {
            float v = W_BIN_C * smsg[k] + unary[a * KK + k];
            e[k] = v;
            if (v > m) m = v;
        }
        float s = 0.f;
        #pragma unroll
        for (int k = 0; k < KK; ++k) { e[k] = expf(e[k] - m); s += e[k]; }
        #pragma unroll
        for (int k = 0; k < KK; ++k) sq[k] = e[k] / s;
    }
    __syncthreads();
    for (int c = t; c < CC; c += 640) {
        float q = 0.f;
        #pragma unroll
        for (int k = 0; k < KK; ++k) if (sL[k] == c) q = sq[k];
        out[a * CC + c] = (roi[a * CC + c] + MIX_C * q) / (1.0f + MIX_C);
    }
}

extern "C" void kernel_launch(void* const* d_in, const int* in_sizes, int n_in,
                              void* d_out, int out_size, void* d_ws, size_t ws_size,
                              hipStream_t stream) {
    const float* roi    = (const float*)d_in[0];  // (128, 1001)
    const float* rel    = (const float*)d_in[1];  // (16384, 51)
    const float* relmat = (const float*)d_in[2];  // (1001, 1001, 51)
    float* out = (float*)d_out;

    // workspace layout (16B-aligned)
    char* ws = (char*)d_ws;
    float* bt     = (float*)ws;                                   // 6,553,600 B
    int*   labels = (int*)(ws + (size_t)BT_ELEMS * 4);            // 5,120 B
    float* unary  = (float*)(ws + (size_t)BT_ELEMS * 4 + 5120);   // 5,120 B
    float* QA     = unary + NK;
    float* QB     = QA + NK;

    topk_kernel<<<NN, 64, 0, stream>>>(roi, labels, unary);
    pair_kernel<<<dim3(NN, NN), 256, 0, stream>>>(rel, relmat, labels, bt);
    round_kernel<<<NN, 640, 0, stream>>>(bt, unary, QA, QA, 1);       // round 1: uniform Q
    round_kernel<<<NN, 640, 0, stream>>>(bt, unary, QA, QB, 0);       // round 2
    round_out_kernel<<<NN, 640, 0, stream>>>(bt, unary, QB, roi, labels, out);  // round 3 + mix
}